// Round 1
// baseline (85.206 us; speedup 1.0000x reference)
//
#include <hip/hip_runtime.h>
#include <hip/hip_bf16.h>

// out[e] = dot(ufeat[src[e]], ifeat[dst[e]]), D=256 fp32.
// One wave64 per edge: lane i loads float4 at element offset i*4 of each row
// (64 lanes x 16B = 1KB = the whole 256-float row, perfectly coalesced),
// per-lane 4-elem dot, 6-step shfl_xor reduction, lane 0 writes out[e].

__global__ __launch_bounds__(256) void edge_dot_kernel(
    const float* __restrict__ ufeat,
    const float* __restrict__ ifeat,
    const int* __restrict__ src,
    const int* __restrict__ dst,
    float* __restrict__ out,
    int E)
{
    const int gtid = blockIdx.x * blockDim.x + threadIdx.x;
    const int edge = gtid >> 6;          // wave index = edge index
    const int lane = threadIdx.x & 63;
    if (edge >= E) return;

    const int s = src[edge];             // wave-uniform address -> HW broadcast
    const int t = dst[edge];

    const float4 a = *reinterpret_cast<const float4*>(
        ufeat + (size_t)s * 256 + (size_t)lane * 4);
    const float4 b = *reinterpret_cast<const float4*>(
        ifeat + (size_t)t * 256 + (size_t)lane * 4);

    float sum = a.x * b.x + a.y * b.y + a.z * b.z + a.w * b.w;

    // wave64 butterfly reduction
    #pragma unroll
    for (int off = 32; off > 0; off >>= 1)
        sum += __shfl_xor(sum, off, 64);

    if (lane == 0) out[edge] = sum;
}

extern "C" void kernel_launch(void* const* d_in, const int* in_sizes, int n_in,
                              void* d_out, int out_size, void* d_ws, size_t ws_size,
                              hipStream_t stream)
{
    const float* ufeat = (const float*)d_in[0];   // (20000, 256) f32
    const float* ifeat = (const float*)d_in[1];   // (50000, 256) f32
    const int*   src   = (const int*)d_in[2];     // (E,) i32
    const int*   dst   = (const int*)d_in[3];     // (E,) i32
    float*       out   = (float*)d_out;           // (E, 1) f32

    const int E = in_sizes[2];

    const int block = 256;                         // 4 waves/block
    const int edgesPerBlock = block / 64;          // 4
    const int grid = (E + edgesPerBlock - 1) / edgesPerBlock;

    edge_dot_kernel<<<grid, block, 0, stream>>>(ufeat, ifeat, src, dst, out, E);
}

// Round 2
// 84.373 us; speedup vs baseline: 1.0099x; 1.0099x over previous
//
#include <hip/hip_runtime.h>
#include <hip/hip_bf16.h>

// out[e] = dot(ufeat[src[e]], ifeat[dst[e]]), D=256 fp32.
// One wave64 per FOUR edges: issue all 8 row loads (2 per edge) before any
// reduction -> 4x memory-level parallelism per wave vs round-1 kernel.
// Lane i loads float4 at element offset i*4 (64 lanes x 16B = full 1KB row).

__global__ __launch_bounds__(256) void edge_dot_kernel(
    const float* __restrict__ ufeat,
    const float* __restrict__ ifeat,
    const int* __restrict__ src,
    const int* __restrict__ dst,
    float* __restrict__ out,
    int E)
{
    const int wid  = (blockIdx.x * blockDim.x + threadIdx.x) >> 6;  // wave id
    const int lane = threadIdx.x & 63;
    const int e0   = wid * 4;
    if (e0 >= E) return;

    // E = 300000 is divisible by 4 and e0 is 16B-aligned into src/dst,
    // but keep a guarded tail for generality (branches are wave-uniform).
    float4 a0, a1, a2, a3, b0, b1, b2, b3;
    int s0, s1, s2, s3, t0, t1, t2, t3;

    if (e0 + 3 < E) {
        const int4 sv = *reinterpret_cast<const int4*>(src + e0);
        const int4 tv = *reinterpret_cast<const int4*>(dst + e0);
        s0 = sv.x; s1 = sv.y; s2 = sv.z; s3 = sv.w;
        t0 = tv.x; t1 = tv.y; t2 = tv.z; t3 = tv.w;

        const size_t lo = (size_t)lane * 4;
        // issue all 8 gathers back-to-back (independent -> 8 loads in flight)
        a0 = *reinterpret_cast<const float4*>(ufeat + (size_t)s0 * 256 + lo);
        b0 = *reinterpret_cast<const float4*>(ifeat + (size_t)t0 * 256 + lo);
        a1 = *reinterpret_cast<const float4*>(ufeat + (size_t)s1 * 256 + lo);
        b1 = *reinterpret_cast<const float4*>(ifeat + (size_t)t1 * 256 + lo);
        a2 = *reinterpret_cast<const float4*>(ufeat + (size_t)s2 * 256 + lo);
        b2 = *reinterpret_cast<const float4*>(ifeat + (size_t)t2 * 256 + lo);
        a3 = *reinterpret_cast<const float4*>(ufeat + (size_t)s3 * 256 + lo);
        b3 = *reinterpret_cast<const float4*>(ifeat + (size_t)t3 * 256 + lo);

        float u0 = a0.x*b0.x + a0.y*b0.y + a0.z*b0.z + a0.w*b0.w;
        float u1 = a1.x*b1.x + a1.y*b1.y + a1.z*b1.z + a1.w*b1.w;
        float u2 = a2.x*b2.x + a2.y*b2.y + a2.z*b2.z + a2.w*b2.w;
        float u3 = a3.x*b3.x + a3.y*b3.y + a3.z*b3.z + a3.w*b3.w;

        // 4 independent wave64 butterflies (good ILP)
        #pragma unroll
        for (int off = 32; off > 0; off >>= 1) {
            u0 += __shfl_xor(u0, off, 64);
            u1 += __shfl_xor(u1, off, 64);
            u2 += __shfl_xor(u2, off, 64);
            u3 += __shfl_xor(u3, off, 64);
        }

        // every lane now holds all 4 sums; lanes 0..3 store coalesced
        float v = u0;
        v = (lane == 1) ? u1 : v;
        v = (lane == 2) ? u2 : v;
        v = (lane == 3) ? u3 : v;
        if (lane < 4) out[e0 + lane] = v;
    } else {
        // tail: per-edge path (at most 3 edges)
        for (int e = e0; e < E; ++e) {
            const int s = src[e];
            const int t = dst[e];
            const size_t lo = (size_t)lane * 4;
            const float4 a = *reinterpret_cast<const float4*>(ufeat + (size_t)s * 256 + lo);
            const float4 b = *reinterpret_cast<const float4*>(ifeat + (size_t)t * 256 + lo);
            float u = a.x*b.x + a.y*b.y + a.z*b.z + a.w*b.w;
            #pragma unroll
            for (int off = 32; off > 0; off >>= 1)
                u += __shfl_xor(u, off, 64);
            if (lane == 0) out[e] = u;
        }
    }
}

extern "C" void kernel_launch(void* const* d_in, const int* in_sizes, int n_in,
                              void* d_out, int out_size, void* d_ws, size_t ws_size,
                              hipStream_t stream)
{
    const float* ufeat = (const float*)d_in[0];   // (20000, 256) f32
    const float* ifeat = (const float*)d_in[1];   // (50000, 256) f32
    const int*   src   = (const int*)d_in[2];     // (E,) i32
    const int*   dst   = (const int*)d_in[3];     // (E,) i32
    float*       out   = (float*)d_out;           // (E, 1) f32

    const int E = in_sizes[2];

    const int block = 256;                          // 4 waves/block
    const int edgesPerBlock = (block / 64) * 4;     // 16 edges/block
    const int grid = (E + edgesPerBlock - 1) / edgesPerBlock;

    edge_dot_kernel<<<grid, block, 0, stream>>>(ufeat, ifeat, src, dst, out, E);
}

// Round 3
// 60.719 us; speedup vs baseline: 1.4033x; 1.3896x over previous
//
#include <hip/hip_runtime.h>
#include <hip/hip_bf16.h>

// out[e] = dot(ufeat[src[e]], ifeat[dst[e]]), D=256 fp32, E=300K.
//
// Round-2 finding: two different kernels both pin at ~3.5 TB/s of L2-miss
// (EA/fabric) bandwidth with FETCH_SIZE ~282MB -> bandwidth-bound past L2,
// not latency-bound. Fix: halve gathered bytes + halve working set by
// converting both tables to fp16 in d_ws first (streaming pre-pass), then
// gather fp16 rows (512B/row = 64 lanes x 8B).

typedef _Float16 half4 __attribute__((ext_vector_type(4)));
typedef _Float16 half8 __attribute__((ext_vector_type(8)));

// ---------------- conversion: fp32 tables -> fp16 in workspace ----------------
__global__ __launch_bounds__(256) void cvt_f32_to_f16(
    const float* __restrict__ u, const float* __restrict__ v,
    _Float16* __restrict__ uh, _Float16* __restrict__ vh,
    int nU, int nTotal)   // element counts (floats), both divisible by 8
{
    int i = blockIdx.x * blockDim.x + threadIdx.x;
    const int stride = gridDim.x * blockDim.x;
    const int total8 = nTotal / 8;
    for (; i < total8; i += stride) {
        const int j = i * 8;
        const float* sp;
        _Float16* dp;
        if (j < nU) { sp = u + j;        dp = uh + j; }
        else        { sp = v + (j - nU); dp = vh + (j - nU); }
        const float4 f0 = *reinterpret_cast<const float4*>(sp);
        const float4 f1 = *reinterpret_cast<const float4*>(sp + 4);
        half8 h;
        h[0] = (_Float16)f0.x; h[1] = (_Float16)f0.y;
        h[2] = (_Float16)f0.z; h[3] = (_Float16)f0.w;
        h[4] = (_Float16)f1.x; h[5] = (_Float16)f1.y;
        h[6] = (_Float16)f1.z; h[7] = (_Float16)f1.w;
        *reinterpret_cast<half8*>(dp) = h;
    }
}

// ---------------- fp16 gather-dot: 4 edges per wave ----------------
__global__ __launch_bounds__(256) void edge_dot_f16(
    const _Float16* __restrict__ uh,
    const _Float16* __restrict__ vh,
    const int* __restrict__ src,
    const int* __restrict__ dst,
    float* __restrict__ out,
    int E)
{
    const int wid  = (blockIdx.x * blockDim.x + threadIdx.x) >> 6;
    const int lane = threadIdx.x & 63;
    const int e0   = wid * 4;
    if (e0 >= E) return;

    const size_t lo = (size_t)lane * 4;   // element offset within row

    if (e0 + 3 < E) {
        const int4 sv = *reinterpret_cast<const int4*>(src + e0);
        const int4 tv = *reinterpret_cast<const int4*>(dst + e0);

        // 8 independent 8B gathers in flight
        const half4 a0 = *reinterpret_cast<const half4*>(uh + (size_t)sv.x * 256 + lo);
        const half4 b0 = *reinterpret_cast<const half4*>(vh + (size_t)tv.x * 256 + lo);
        const half4 a1 = *reinterpret_cast<const half4*>(uh + (size_t)sv.y * 256 + lo);
        const half4 b1 = *reinterpret_cast<const half4*>(vh + (size_t)tv.y * 256 + lo);
        const half4 a2 = *reinterpret_cast<const half4*>(uh + (size_t)sv.z * 256 + lo);
        const half4 b2 = *reinterpret_cast<const half4*>(vh + (size_t)tv.z * 256 + lo);
        const half4 a3 = *reinterpret_cast<const half4*>(uh + (size_t)sv.w * 256 + lo);
        const half4 b3 = *reinterpret_cast<const half4*>(vh + (size_t)tv.w * 256 + lo);

        float u0 = 0.f, u1 = 0.f, u2 = 0.f, u3 = 0.f;
        #pragma unroll
        for (int k = 0; k < 4; ++k) {
            u0 += (float)a0[k] * (float)b0[k];
            u1 += (float)a1[k] * (float)b1[k];
            u2 += (float)a2[k] * (float)b2[k];
            u3 += (float)a3[k] * (float)b3[k];
        }

        #pragma unroll
        for (int off = 32; off > 0; off >>= 1) {
            u0 += __shfl_xor(u0, off, 64);
            u1 += __shfl_xor(u1, off, 64);
            u2 += __shfl_xor(u2, off, 64);
            u3 += __shfl_xor(u3, off, 64);
        }

        float v = u0;
        v = (lane == 1) ? u1 : v;
        v = (lane == 2) ? u2 : v;
        v = (lane == 3) ? u3 : v;
        if (lane < 4) out[e0 + lane] = v;
    } else {
        for (int e = e0; e < E; ++e) {
            const half4 a = *reinterpret_cast<const half4*>(uh + (size_t)src[e] * 256 + lo);
            const half4 b = *reinterpret_cast<const half4*>(vh + (size_t)dst[e] * 256 + lo);
            float u = 0.f;
            #pragma unroll
            for (int k = 0; k < 4; ++k) u += (float)a[k] * (float)b[k];
            #pragma unroll
            for (int off = 32; off > 0; off >>= 1) u += __shfl_xor(u, off, 64);
            if (lane == 0) out[e] = u;
        }
    }
}

// ---------------- fp32 fallback (round-2 kernel) if ws too small ----------------
__global__ __launch_bounds__(256) void edge_dot_f32(
    const float* __restrict__ ufeat,
    const float* __restrict__ ifeat,
    const int* __restrict__ src,
    const int* __restrict__ dst,
    float* __restrict__ out,
    int E)
{
    const int wid  = (blockIdx.x * blockDim.x + threadIdx.x) >> 6;
    const int lane = threadIdx.x & 63;
    const int e0   = wid * 4;
    if (e0 >= E) return;
    const size_t lo = (size_t)lane * 4;

    for (int e = e0; e < min(e0 + 4, E); ++e) {
        const float4 a = *reinterpret_cast<const float4*>(ufeat + (size_t)src[e] * 256 + lo);
        const float4 b = *reinterpret_cast<const float4*>(ifeat + (size_t)dst[e] * 256 + lo);
        float u = a.x*b.x + a.y*b.y + a.z*b.z + a.w*b.w;
        #pragma unroll
        for (int off = 32; off > 0; off >>= 1) u += __shfl_xor(u, off, 64);
        if (lane == 0) out[e] = u;
    }
}

extern "C" void kernel_launch(void* const* d_in, const int* in_sizes, int n_in,
                              void* d_out, int out_size, void* d_ws, size_t ws_size,
                              hipStream_t stream)
{
    const float* ufeat = (const float*)d_in[0];   // (20000, 256) f32
    const float* ifeat = (const float*)d_in[1];   // (50000, 256) f32
    const int*   src   = (const int*)d_in[2];     // (E,) i32
    const int*   dst   = (const int*)d_in[3];     // (E,) i32
    float*       out   = (float*)d_out;           // (E, 1) f32

    const int E  = in_sizes[2];
    const int nU = in_sizes[0];                   // 20000*256 = 5,120,000
    const int nV = in_sizes[1];                   // 50000*256 = 12,800,000
    const size_t needBytes = (size_t)(nU + nV) * sizeof(_Float16);  // 35.84 MB

    const int block = 256;
    const int edgesPerBlock = (block / 64) * 4;   // 16 edges/block
    const int grid = (E + edgesPerBlock - 1) / edgesPerBlock;

    if (ws_size >= needBytes) {
        _Float16* uh = (_Float16*)d_ws;
        _Float16* vh = uh + nU;                   // offset 10,240,000 B (16B-aligned)

        const int cvtGrid = 2048;                 // grid-stride over 2.24M items
        cvt_f32_to_f16<<<cvtGrid, block, 0, stream>>>(ufeat, ifeat, uh, vh,
                                                      nU, nU + nV);
        edge_dot_f16<<<grid, block, 0, stream>>>(uh, vh, src, dst, out, E);
    } else {
        edge_dot_f32<<<grid, block, 0, stream>>>(ufeat, ifeat, src, dst, out, E);
    }
}